// Round 5
// baseline (265.529 us; speedup 1.0000x reference)
//
#include <hip/hip_runtime.h>
#include <math.h>

// Problem size: B*C*H*W = 64*1*512*512
#define N_TOTAL 16777216
#define ACC_COUNT 5       // sx, st, sx2, sxt, sb(log2-space)   (st2 == st since t in {0,1})
#define MAX_BLOCKS 2048

// t is EXACTLY 0.0f or 1.0f, so the BCE blend selects one term:
//   max(log(t ? x : 1-x), -100)  ==  ln2 * max(log2(arg), -100/ln2)
#define ELEM_BODY(x, t)                                        \
    do {                                                       \
        float omx = 1.0f - (x);                                \
        sx += (x);                                             \
        st += (t);                                             \
        sx2 = fmaf((x), (x), sx2);                             \
        sxt = fmaf((x), (t), sxt);                             \
        float arg = fmaf((t), (x) - omx, omx); /* t?x:1-x */   \
        float l2  = fmaxf(__log2f(arg), -144.26950408889634f); \
        sb += l2;                                              \
    } while (0)

#define ELEM4(xv, tv)             \
    do {                          \
        ELEM_BODY((xv).x, (tv).x);\
        ELEM_BODY((xv).y, (tv).y);\
        ELEM_BODY((xv).z, (tv).z);\
        ELEM_BODY((xv).w, (tv).w);\
    } while (0)

__global__ __launch_bounds__(256) void loss_fused_kernel(
    const float4* __restrict__ x4,
    const float4* __restrict__ t4,
    float* __restrict__ partials,       // SoA: partials[k*MAX_BLOCKS + blk]
    unsigned int* __restrict__ counter, // zeroed by host each call
    float* __restrict__ out,
    int n4)
{
    float sx = 0.f, st = 0.f, sx2 = 0.f, sxt = 0.f, sb = 0.f;

    const int tid    = blockIdx.x * blockDim.x + threadIdx.x;
    const int stride = gridDim.x * blockDim.x;

    int i = tid;

    // ---- main loop: 4-way unrolled, all 8 loads issued before first use ----
    for (; i + 3 * stride < n4; i += 4 * stride) {
        float4 xv0 = x4[i];
        float4 xv1 = x4[i + stride];
        float4 xv2 = x4[i + 2 * stride];
        float4 xv3 = x4[i + 3 * stride];
        float4 tv0 = t4[i];
        float4 tv1 = t4[i + stride];
        float4 tv2 = t4[i + 2 * stride];
        float4 tv3 = t4[i + 3 * stride];

        ELEM4(xv0, tv0);
        ELEM4(xv1, tv1);
        ELEM4(xv2, tv2);
        ELEM4(xv3, tv3);
    }

    // ---- tail ----
    for (; i < n4; i += stride) {
        float4 xv = x4[i];
        float4 tv = t4[i];
        ELEM4(xv, tv);
    }

    // ---- wave (64-lane) reduction ----
    #pragma unroll
    for (int off = 32; off > 0; off >>= 1) {
        sx  += __shfl_down(sx,  off);
        st  += __shfl_down(st,  off);
        sx2 += __shfl_down(sx2, off);
        sxt += __shfl_down(sxt, off);
        sb  += __shfl_down(sb,  off);
    }

    // ---- block reduction across 4 waves ----
    __shared__ float lds[4][ACC_COUNT];
    int lane = threadIdx.x & 63;
    int wid  = threadIdx.x >> 6;
    if (lane == 0) {
        lds[wid][0] = sx;  lds[wid][1] = st;  lds[wid][2] = sx2;
        lds[wid][3] = sxt; lds[wid][4] = sb;
    }
    __syncthreads();

    if (threadIdx.x < ACC_COUNT) {
        int k = threadIdx.x;
        float v = lds[0][k] + lds[1][k] + lds[2][k] + lds[3][k];
        partials[k * MAX_BLOCKS + blockIdx.x] = v;   // plain store, no atomics
    }

    // ---- last-block finalize (device-scope ticket; Guideline 16) ----
    __shared__ int is_last;
    __threadfence();                       // make partials visible device-wide
    if (threadIdx.x == 0) {
        unsigned int prev = atomicAdd(counter, 1u);   // device-scope
        is_last = (prev == (unsigned int)(gridDim.x - 1));
    }
    __syncthreads();
    if (!is_last) return;
    __threadfence();                       // acquire: see all partials

    const int nblocks = gridDim.x;
    double a[ACC_COUNT] = {0, 0, 0, 0, 0};
    for (int r = threadIdx.x; r < nblocks; r += blockDim.x) {
        #pragma unroll
        for (int k = 0; k < ACC_COUNT; ++k)
            a[k] += (double)partials[k * MAX_BLOCKS + r];
    }

    #pragma unroll
    for (int off = 32; off > 0; off >>= 1) {
        #pragma unroll
        for (int k = 0; k < ACC_COUNT; ++k)
            a[k] += __shfl_down(a[k], off);
    }

    __shared__ double dlds[4][ACC_COUNT];
    if (lane == 0) {
        #pragma unroll
        for (int k = 0; k < ACC_COUNT; ++k) dlds[wid][k] = a[k];
    }
    __syncthreads();

    if (threadIdx.x == 0) {
        double fsx  = dlds[0][0] + dlds[1][0] + dlds[2][0] + dlds[3][0];
        double fst  = dlds[0][1] + dlds[1][1] + dlds[2][1] + dlds[3][1];
        double fsx2 = dlds[0][2] + dlds[1][2] + dlds[2][2] + dlds[3][2];
        double fsxt = dlds[0][3] + dlds[1][3] + dlds[2][3] + dlds[3][3];
        double fsb  = dlds[0][4] + dlds[1][4] + dlds[2][4] + dlds[3][4];

        const double n = (double)N_TOTAL;
        const double LN2 = 0.6931471805599453;

        // BCE (fsb is in log2 space)
        double bce = -(fsb * LN2) / n;

        // NCC (Σt² == Σt exactly, since t ∈ {0,1})
        double xm = fsx / n;
        double tm = fst / n;
        double xs = sqrt((fsx2 - fsx * fsx / n) / (n - 1.0));
        double ts = sqrt((fst  - fst * fst / n) / (n - 1.0));
        double ncc = (fsxt - n * xm * tm) / (xs * ts * n);

        // Tversky
        const double beta = 0.1, adding = 1.0;
        double TP = fsxt;
        double FP = fsx - fsxt;
        double FN = fst - fsxt;
        double tversky = (TP + adding) / (TP + beta * FP + (1.0 - beta) * FN + adding);

        const double alpha = 0.5;
        double res = (1.0 - (alpha * ncc + (1.0 - alpha) * tversky)) * bce;

        out[0] = (float)res;
    }
}

extern "C" void kernel_launch(void* const* d_in, const int* in_sizes, int n_in,
                              void* d_out, int out_size, void* d_ws, size_t ws_size,
                              hipStream_t stream)
{
    const float* x = (const float*)d_in[0];
    const float* t = (const float*)d_in[1];
    float* out = (float*)d_out;

    float* partials = (float*)d_ws;                       // 5 * MAX_BLOCKS floats
    unsigned int* counter =
        (unsigned int*)((char*)d_ws + ACC_COUNT * MAX_BLOCKS * sizeof(float));

    int n  = in_sizes[0];
    int n4 = n / 4;

    // d_ws is NOT re-poisoned between replays — zero the ticket each call.
    hipMemsetAsync(counter, 0, sizeof(unsigned int), stream);

    const int block = 256;
    int grid = (n4 + block - 1) / block;
    if (grid > MAX_BLOCKS) grid = MAX_BLOCKS;

    loss_fused_kernel<<<grid, block, 0, stream>>>(
        (const float4*)x, (const float4*)t, partials, counter, out, n4);
}

// Round 6
// 32.238 us; speedup vs baseline: 8.2364x; 8.2364x over previous
//
#include <hip/hip_runtime.h>
#include <math.h>

// Problem size: B*C*H*W = 64*1*512*512
#define N_TOTAL   16777216
#define ACC_COUNT 5        // sx, st, sx2, sxt, sb(log2-space)  (st2 == st since t in {0,1})
#define BLOCK     256
#define F4_PER_THREAD 4    // straight-line: 4 float4 per array per thread
#define GRID  (N_TOTAL / 4 / BLOCK / F4_PER_THREAD)   // 4096 blocks

// t is EXACTLY 0.0f or 1.0f, so the BCE blend selects one term:
//   max(log(t ? x : 1-x), -100)  ==  ln2 * max(log2(arg), -100/ln2)
#define ELEM_BODY(x, t)                                        \
    do {                                                       \
        float omx = 1.0f - (x);                                \
        sx += (x);                                             \
        st += (t);                                             \
        sx2 = fmaf((x), (x), sx2);                             \
        sxt = fmaf((x), (t), sxt);                             \
        float arg = fmaf((t), (x) - omx, omx); /* t?x:1-x */   \
        float l2  = fmaxf(__log2f(arg), -144.26950408889634f); \
        sb += l2;                                              \
    } while (0)

#define ELEM4(xv, tv)              \
    do {                           \
        ELEM_BODY((xv).x, (tv).x); \
        ELEM_BODY((xv).y, (tv).y); \
        ELEM_BODY((xv).z, (tv).z); \
        ELEM_BODY((xv).w, (tv).w); \
    } while (0)

__global__ __launch_bounds__(BLOCK) void loss_reduce_kernel(
    const float4* __restrict__ x4,
    const float4* __restrict__ t4,
    float* __restrict__ partials)   // SoA: partials[k*GRID + blockIdx.x]
{
    // Block-tiled, straight-line: block owns a contiguous 1024-float4 tile,
    // thread loads tile[tid], tile[tid+256], tile[tid+512], tile[tid+768]
    // from BOTH arrays — 8 independent 16B loads all in flight before use.
    const int base = blockIdx.x * (BLOCK * F4_PER_THREAD) + threadIdx.x;

    float4 xv0 = x4[base];
    float4 xv1 = x4[base + BLOCK];
    float4 xv2 = x4[base + 2 * BLOCK];
    float4 xv3 = x4[base + 3 * BLOCK];
    float4 tv0 = t4[base];
    float4 tv1 = t4[base + BLOCK];
    float4 tv2 = t4[base + 2 * BLOCK];
    float4 tv3 = t4[base + 3 * BLOCK];

    float sx = 0.f, st = 0.f, sx2 = 0.f, sxt = 0.f, sb = 0.f;

    ELEM4(xv0, tv0);
    ELEM4(xv1, tv1);
    ELEM4(xv2, tv2);
    ELEM4(xv3, tv3);

    // ---- wave (64-lane) reduction ----
    #pragma unroll
    for (int off = 32; off > 0; off >>= 1) {
        sx  += __shfl_down(sx,  off);
        st  += __shfl_down(st,  off);
        sx2 += __shfl_down(sx2, off);
        sxt += __shfl_down(sxt, off);
        sb  += __shfl_down(sb,  off);
    }

    // ---- block reduction across 4 waves ----
    __shared__ float lds[4][ACC_COUNT];
    int lane = threadIdx.x & 63;
    int wid  = threadIdx.x >> 6;
    if (lane == 0) {
        lds[wid][0] = sx;  lds[wid][1] = st;  lds[wid][2] = sx2;
        lds[wid][3] = sxt; lds[wid][4] = sb;
    }
    __syncthreads();

    if (threadIdx.x < ACC_COUNT) {
        int k = threadIdx.x;
        float v = lds[0][k] + lds[1][k] + lds[2][k] + lds[3][k];
        partials[k * GRID + blockIdx.x] = v;   // plain store, no atomics
    }
}

__global__ __launch_bounds__(BLOCK) void loss_finalize_kernel(
    const float* __restrict__ partials,
    float* __restrict__ out)
{
    double a[ACC_COUNT] = {0, 0, 0, 0, 0};

    for (int r = threadIdx.x; r < GRID; r += BLOCK) {
        #pragma unroll
        for (int k = 0; k < ACC_COUNT; ++k)
            a[k] += (double)partials[k * GRID + r];
    }

    #pragma unroll
    for (int off = 32; off > 0; off >>= 1) {
        #pragma unroll
        for (int k = 0; k < ACC_COUNT; ++k)
            a[k] += __shfl_down(a[k], off);
    }

    __shared__ double lds[4][ACC_COUNT];
    int lane = threadIdx.x & 63;
    int wid  = threadIdx.x >> 6;
    if (lane == 0) {
        #pragma unroll
        for (int k = 0; k < ACC_COUNT; ++k) lds[wid][k] = a[k];
    }
    __syncthreads();

    if (threadIdx.x == 0) {
        double sx  = lds[0][0] + lds[1][0] + lds[2][0] + lds[3][0];
        double st  = lds[0][1] + lds[1][1] + lds[2][1] + lds[3][1];
        double sx2 = lds[0][2] + lds[1][2] + lds[2][2] + lds[3][2];
        double sxt = lds[0][3] + lds[1][3] + lds[2][3] + lds[3][3];
        double sb  = lds[0][4] + lds[1][4] + lds[2][4] + lds[3][4];

        const double n = (double)N_TOTAL;
        const double LN2 = 0.6931471805599453;

        // BCE (sb is in log2 space)
        double bce = -(sb * LN2) / n;

        // NCC (Σt² == Σt exactly, since t ∈ {0,1})
        double xm = sx / n;
        double tm = st / n;
        double xs = sqrt((sx2 - sx * sx / n) / (n - 1.0));
        double ts = sqrt((st  - st * st / n) / (n - 1.0));
        double ncc = (sxt - n * xm * tm) / (xs * ts * n);

        // Tversky
        const double beta = 0.1, adding = 1.0;
        double TP = sxt;
        double FP = sx - sxt;
        double FN = st - sxt;
        double tversky = (TP + adding) / (TP + beta * FP + (1.0 - beta) * FN + adding);

        const double alpha = 0.5;
        double res = (1.0 - (alpha * ncc + (1.0 - alpha) * tversky)) * bce;

        out[0] = (float)res;
    }
}

extern "C" void kernel_launch(void* const* d_in, const int* in_sizes, int n_in,
                              void* d_out, int out_size, void* d_ws, size_t ws_size,
                              hipStream_t stream)
{
    const float* x = (const float*)d_in[0];
    const float* t = (const float*)d_in[1];
    float* out = (float*)d_out;
    float* partials = (float*)d_ws;    // ACC_COUNT * GRID floats = 80 KB

    loss_reduce_kernel<<<GRID, BLOCK, 0, stream>>>(
        (const float4*)x, (const float4*)t, partials);
    loss_finalize_kernel<<<1, BLOCK, 0, stream>>>(partials, out);
}

// Round 7
// 30.027 us; speedup vs baseline: 8.8431x; 1.0737x over previous
//
#include <hip/hip_runtime.h>
#include <math.h>

// Problem size: B*C*H*W = 64*1*512*512
#define N_TOTAL   16777216
#define ACC_COUNT 5        // sx, st, sx2, sxt, sb(log2-space)  (st2 == st since t in {0,1})
#define BLOCK     256
#define F4_PER_THREAD 4    // straight-line: 4 float4 per array per thread
#define GRID  (N_TOTAL / 4 / BLOCK / F4_PER_THREAD)   // 4096 blocks
#define FIN_BLOCK 1024     // finalize: 1024 thr × float4 = 4096 partials in ONE round

// t is EXACTLY 0.0f or 1.0f, so the BCE blend selects one term:
//   max(log(t ? x : 1-x), -100)  ==  ln2 * max(log2(arg), -100/ln2)
#define ELEM_BODY(x, t)                                        \
    do {                                                       \
        float omx = 1.0f - (x);                                \
        sx += (x);                                             \
        st += (t);                                             \
        sx2 = fmaf((x), (x), sx2);                             \
        sxt = fmaf((x), (t), sxt);                             \
        float arg = fmaf((t), (x) - omx, omx); /* t?x:1-x */   \
        float l2  = fmaxf(__log2f(arg), -144.26950408889634f); \
        sb += l2;                                              \
    } while (0)

#define ELEM4(xv, tv)              \
    do {                           \
        ELEM_BODY((xv).x, (tv).x); \
        ELEM_BODY((xv).y, (tv).y); \
        ELEM_BODY((xv).z, (tv).z); \
        ELEM_BODY((xv).w, (tv).w); \
    } while (0)

__global__ __launch_bounds__(BLOCK) void loss_reduce_kernel(
    const float4* __restrict__ x4,
    const float4* __restrict__ t4,
    float* __restrict__ partials)   // SoA: partials[k*GRID + blockIdx.x]
{
    const int base = blockIdx.x * (BLOCK * F4_PER_THREAD) + threadIdx.x;

    float4 xv0 = x4[base];
    float4 xv1 = x4[base + BLOCK];
    float4 xv2 = x4[base + 2 * BLOCK];
    float4 xv3 = x4[base + 3 * BLOCK];
    float4 tv0 = t4[base];
    float4 tv1 = t4[base + BLOCK];
    float4 tv2 = t4[base + 2 * BLOCK];
    float4 tv3 = t4[base + 3 * BLOCK];

    float sx = 0.f, st = 0.f, sx2 = 0.f, sxt = 0.f, sb = 0.f;

    ELEM4(xv0, tv0);
    ELEM4(xv1, tv1);
    ELEM4(xv2, tv2);
    ELEM4(xv3, tv3);

    // ---- wave (64-lane) reduction ----
    #pragma unroll
    for (int off = 32; off > 0; off >>= 1) {
        sx  += __shfl_down(sx,  off);
        st  += __shfl_down(st,  off);
        sx2 += __shfl_down(sx2, off);
        sxt += __shfl_down(sxt, off);
        sb  += __shfl_down(sb,  off);
    }

    // ---- block reduction across 4 waves ----
    __shared__ float lds[4][ACC_COUNT];
    int lane = threadIdx.x & 63;
    int wid  = threadIdx.x >> 6;
    if (lane == 0) {
        lds[wid][0] = sx;  lds[wid][1] = st;  lds[wid][2] = sx2;
        lds[wid][3] = sxt; lds[wid][4] = sb;
    }
    __syncthreads();

    if (threadIdx.x < ACC_COUNT) {
        int k = threadIdx.x;
        float v = lds[0][k] + lds[1][k] + lds[2][k] + lds[3][k];
        partials[k * GRID + blockIdx.x] = v;   // plain store, no atomics
    }
}

__global__ __launch_bounds__(FIN_BLOCK) void loss_finalize_kernel(
    const float4* __restrict__ partials4,   // same buffer, viewed as float4
    float* __restrict__ out)
{
    // GRID = 4096 partials per accumulator row; 1024 threads × float4 = one round.
    const int tid = threadIdx.x;
    const int row_f4 = GRID / 4;   // 1024 float4 per row

    double a[ACC_COUNT];
    #pragma unroll
    for (int k = 0; k < ACC_COUNT; ++k) {
        float4 v = partials4[k * row_f4 + tid];   // 5 independent 16B loads
        a[k] = (double)v.x + (double)v.y + (double)v.z + (double)v.w;
    }

    // ---- wave (64-lane) reduction of 5 doubles ----
    #pragma unroll
    for (int off = 32; off > 0; off >>= 1) {
        #pragma unroll
        for (int k = 0; k < ACC_COUNT; ++k)
            a[k] += __shfl_down(a[k], off);
    }

    // ---- block reduction across 16 waves ----
    __shared__ double lds[16][ACC_COUNT];
    int lane = tid & 63;
    int wid  = tid >> 6;
    if (lane == 0) {
        #pragma unroll
        for (int k = 0; k < ACC_COUNT; ++k) lds[wid][k] = a[k];
    }
    __syncthreads();

    if (tid == 0) {
        double s[ACC_COUNT] = {0, 0, 0, 0, 0};
        #pragma unroll
        for (int w = 0; w < 16; ++w)
            #pragma unroll
            for (int k = 0; k < ACC_COUNT; ++k)
                s[k] += lds[w][k];

        double sx  = s[0];
        double st  = s[1];
        double sx2 = s[2];
        double sxt = s[3];
        double sb  = s[4];

        const double n = (double)N_TOTAL;
        const double LN2 = 0.6931471805599453;

        // BCE (sb is in log2 space)
        double bce = -(sb * LN2) / n;

        // NCC (Σt² == Σt exactly, since t ∈ {0,1})
        double xm = sx / n;
        double tm = st / n;
        double xs = sqrt((sx2 - sx * sx / n) / (n - 1.0));
        double ts = sqrt((st  - st * st / n) / (n - 1.0));
        double ncc = (sxt - n * xm * tm) / (xs * ts * n);

        // Tversky
        const double beta = 0.1, adding = 1.0;
        double TP = sxt;
        double FP = sx - sxt;
        double FN = st - sxt;
        double tversky = (TP + adding) / (TP + beta * FP + (1.0 - beta) * FN + adding);

        const double alpha = 0.5;
        double res = (1.0 - (alpha * ncc + (1.0 - alpha) * tversky)) * bce;

        out[0] = (float)res;
    }
}

extern "C" void kernel_launch(void* const* d_in, const int* in_sizes, int n_in,
                              void* d_out, int out_size, void* d_ws, size_t ws_size,
                              hipStream_t stream)
{
    const float* x = (const float*)d_in[0];
    const float* t = (const float*)d_in[1];
    float* out = (float*)d_out;
    float* partials = (float*)d_ws;    // ACC_COUNT * GRID floats = 80 KB (16B-aligned)

    loss_reduce_kernel<<<GRID, BLOCK, 0, stream>>>(
        (const float4*)x, (const float4*)t, partials);
    loss_finalize_kernel<<<1, FIN_BLOCK, 0, stream>>>(
        (const float4*)partials, out);
}

// Round 8
// 28.074 us; speedup vs baseline: 9.4580x; 1.0695x over previous
//
#include <hip/hip_runtime.h>
#include <math.h>

// Problem size: B*C*H*W = 64*1*512*512
#define N_TOTAL   16777216
#define ACC_COUNT 5        // sx, st, sx2, sxt, sb(log2-space)  (st2 == st since t in {0,1})
#define BLOCK     256
#define F4_PER_THREAD 8    // 8 float4 per array per thread, in 2 batches of 4
#define GRID  (N_TOTAL / 4 / BLOCK / F4_PER_THREAD)   // 2048 blocks
#define FIN_BLOCK 512      // finalize: 512 thr × float4 = 2048 partials in ONE round

// t is EXACTLY 0.0f or 1.0f, so the BCE blend selects one term:
//   max(log(t ? x : 1-x), -100)  ==  ln2 * max(log2(arg), -100/ln2)
#define ELEM_BODY(x, t)                                        \
    do {                                                       \
        float omx = 1.0f - (x);                                \
        sx += (x);                                             \
        st += (t);                                             \
        sx2 = fmaf((x), (x), sx2);                             \
        sxt = fmaf((x), (t), sxt);                             \
        float arg = fmaf((t), (x) - omx, omx); /* t?x:1-x */   \
        float l2  = fmaxf(__log2f(arg), -144.26950408889634f); \
        sb += l2;                                              \
    } while (0)

#define ELEM4(xv, tv)              \
    do {                           \
        ELEM_BODY((xv).x, (tv).x); \
        ELEM_BODY((xv).y, (tv).y); \
        ELEM_BODY((xv).z, (tv).z); \
        ELEM_BODY((xv).w, (tv).w); \
    } while (0)

__global__ __launch_bounds__(BLOCK) void loss_reduce_kernel(
    const float4* __restrict__ x4,
    const float4* __restrict__ t4,
    float* __restrict__ partials)   // SoA: partials[k*GRID + blockIdx.x]
{
    float sx = 0.f, st = 0.f, sx2 = 0.f, sxt = 0.f, sb = 0.f;

    const int base = blockIdx.x * (BLOCK * F4_PER_THREAD) + threadIdx.x;

    // Two batches of (4 x-loads + 4 t-loads): 8 independent 16B loads in
    // flight per batch; VGPR stays low enough for 8 waves/SIMD.
    #pragma unroll 2
    for (int b = 0; b < 2; ++b) {
        const int o = base + b * (4 * BLOCK);
        float4 xv0 = x4[o];
        float4 xv1 = x4[o + BLOCK];
        float4 xv2 = x4[o + 2 * BLOCK];
        float4 xv3 = x4[o + 3 * BLOCK];
        float4 tv0 = t4[o];
        float4 tv1 = t4[o + BLOCK];
        float4 tv2 = t4[o + 2 * BLOCK];
        float4 tv3 = t4[o + 3 * BLOCK];

        ELEM4(xv0, tv0);
        ELEM4(xv1, tv1);
        ELEM4(xv2, tv2);
        ELEM4(xv3, tv3);
    }

    // ---- wave (64-lane) reduction ----
    #pragma unroll
    for (int off = 32; off > 0; off >>= 1) {
        sx  += __shfl_down(sx,  off);
        st  += __shfl_down(st,  off);
        sx2 += __shfl_down(sx2, off);
        sxt += __shfl_down(sxt, off);
        sb  += __shfl_down(sb,  off);
    }

    // ---- block reduction across 4 waves ----
    __shared__ float lds[4][ACC_COUNT];
    int lane = threadIdx.x & 63;
    int wid  = threadIdx.x >> 6;
    if (lane == 0) {
        lds[wid][0] = sx;  lds[wid][1] = st;  lds[wid][2] = sx2;
        lds[wid][3] = sxt; lds[wid][4] = sb;
    }
    __syncthreads();

    if (threadIdx.x < ACC_COUNT) {
        int k = threadIdx.x;
        float v = lds[0][k] + lds[1][k] + lds[2][k] + lds[3][k];
        partials[k * GRID + blockIdx.x] = v;   // plain store, no atomics
    }
}

__global__ __launch_bounds__(FIN_BLOCK) void loss_finalize_kernel(
    const float4* __restrict__ partials4,   // same buffer, viewed as float4
    float* __restrict__ out)
{
    // GRID = 2048 partials per accumulator row; 512 threads × float4 = one round.
    const int tid = threadIdx.x;
    const int row_f4 = GRID / 4;   // 512 float4 per row

    double a[ACC_COUNT];
    #pragma unroll
    for (int k = 0; k < ACC_COUNT; ++k) {
        float4 v = partials4[k * row_f4 + tid];   // 5 independent 16B loads
        a[k] = (double)v.x + (double)v.y + (double)v.z + (double)v.w;
    }

    // ---- wave (64-lane) reduction of 5 doubles ----
    #pragma unroll
    for (int off = 32; off > 0; off >>= 1) {
        #pragma unroll
        for (int k = 0; k < ACC_COUNT; ++k)
            a[k] += __shfl_down(a[k], off);
    }

    // ---- block reduction across 8 waves ----
    __shared__ double lds[8][ACC_COUNT];
    int lane = tid & 63;
    int wid  = tid >> 6;
    if (lane == 0) {
        #pragma unroll
        for (int k = 0; k < ACC_COUNT; ++k) lds[wid][k] = a[k];
    }
    __syncthreads();

    if (tid == 0) {
        double s[ACC_COUNT] = {0, 0, 0, 0, 0};
        #pragma unroll
        for (int w = 0; w < 8; ++w)
            #pragma unroll
            for (int k = 0; k < ACC_COUNT; ++k)
                s[k] += lds[w][k];

        double sx  = s[0];
        double st  = s[1];
        double sx2 = s[2];
        double sxt = s[3];
        double sb  = s[4];

        const double n = (double)N_TOTAL;
        const double LN2 = 0.6931471805599453;

        // BCE (sb is in log2 space)
        double bce = -(sb * LN2) / n;

        // NCC (Σt² == Σt exactly, since t ∈ {0,1})
        double xm = sx / n;
        double tm = st / n;
        double xs = sqrt((sx2 - sx * sx / n) / (n - 1.0));
        double ts = sqrt((st  - st * st / n) / (n - 1.0));
        double ncc = (sxt - n * xm * tm) / (xs * ts * n);

        // Tversky
        const double beta = 0.1, adding = 1.0;
        double TP = sxt;
        double FP = sx - sxt;
        double FN = st - sxt;
        double tversky = (TP + adding) / (TP + beta * FP + (1.0 - beta) * FN + adding);

        const double alpha = 0.5;
        double res = (1.0 - (alpha * ncc + (1.0 - alpha) * tversky)) * bce;

        out[0] = (float)res;
    }
}

extern "C" void kernel_launch(void* const* d_in, const int* in_sizes, int n_in,
                              void* d_out, int out_size, void* d_ws, size_t ws_size,
                              hipStream_t stream)
{
    const float* x = (const float*)d_in[0];
    const float* t = (const float*)d_in[1];
    float* out = (float*)d_out;
    float* partials = (float*)d_ws;    // ACC_COUNT * GRID floats = 40 KB (16B-aligned)

    loss_reduce_kernel<<<GRID, BLOCK, 0, stream>>>(
        (const float4*)x, (const float4*)t, partials);
    loss_finalize_kernel<<<1, FIN_BLOCK, 0, stream>>>(
        (const float4*)partials, out);
}